// Round 5
// baseline (1732.650 us; speedup 1.0000x reference)
//
#include <hip/hip_runtime.h>
#include <cstdint>

#define RES 4096
#define N_CELLS (RES*RES)

// ================= fused temporal-blocked Jacobi =================
// 4 launches x 5 steps = 20 sweeps. V in LDS + per-thread regs; packed in regs.
#define T_STEPS 5
#define OW 128
#define OH 64
#define HALO_V 5
#define HALO_H 8                    // >=5 needed; 8 keeps float4 alignment
#define IW (OW + 2*HALO_H)          // 144
#define IH (OH + 2*HALO_V)          // 74
#define NF4 (IW/4)                  // 36
#define NSLOT (NF4*IH)              // 2664
#define NTHR 512
#define NITER ((NSLOT + NTHR - 1)/NTHR)  // 6
#define LDSW 144                    // row stride in floats (16B-aligned rows)

// desc packing: bits[0:13]=lo, [14:20]=lrow, [21:26]=lcol4, <0 = inactive
template<int FINAL>
__global__ __launch_bounds__(NTHR, 6) void lap_fused(
    const float* __restrict__ Vin, const uint32_t* __restrict__ packed,
    float* __restrict__ Vout)
{
    __shared__ float lds_raw[IH * LDSW + 8];   // +8: pad for lo-4 / lo+4 reads
    float* lds = lds_raw + 4;                  // 16B-aligned base offset
    const int tid = threadIdx.x;
    const int r0 = blockIdx.y * OH;
    const int c0 = blockIdx.x * OW;

    float4 v[NITER];
    uint4  pk[NITER];
    int    desc[NITER];

    // ---- stage: global -> regs + LDS ----
#pragma unroll
    for (int k = 0; k < NITER; ++k) {
        const int idx = tid + k * NTHR;
        if (idx < NSLOT) {
            const int lrow  = idx / NF4;          // const-divisor -> mulhi
            const int lcol4 = idx - lrow * NF4;
            const int gr = r0 - HALO_V + lrow;
            const int gc = c0 - HALO_H + lcol4 * 4;
            const int lo = lrow * LDSW + lcol4 * 4;
            desc[k] = lo | (lrow << 14) | (lcol4 << 21);
            float4 vv; uint4 pp;
            const int rr = gr < 0 ? 0 : (gr > RES-1 ? RES-1 : gr);
            if (gc >= 0 && gc + 3 <= RES-1) {
                vv = *(const float4*)(Vin    + (size_t)rr * RES + gc);
                pp = *(const uint4*) (packed + (size_t)rr * RES + gc);
            } else {
#pragma unroll
                for (int e = 0; e < 4; ++e) {
                    int cc = gc + e; cc = cc < 0 ? 0 : (cc > RES-1 ? RES-1 : cc);
                    ((float*)&vv)[e]    = Vin   [(size_t)rr * RES + cc];
                    ((uint32_t*)&pp)[e] = packed[(size_t)rr * RES + cc];
                }
            }
            *(float4*)(&lds[lo]) = vv;
            v[k] = vv; pk[k] = pp;
        } else {
            desc[k] = -1;
            v[k] = make_float4(0.f,0.f,0.f,0.f);
            pk[k] = make_uint4(0u,0u,0u,0u);
        }
    }
    __syncthreads();

    // ---- T_STEPS Jacobi steps on the shrinking pyramid ----
    for (int s = 1; s <= T_STEPS; ++s) {
        const int rlo = (r0 == 0)        ? 0   : (r0 - HALO_V + s);
        const int rhi = (r0 + OH == RES) ? RES : (r0 + OH + HALO_V - s);
        const int clo = (c0 == 0)        ? 0   : (c0 - HALO_H + s);
        const int chi = (c0 + OW == RES) ? RES : (c0 + OW + HALO_H - s);
#pragma unroll
        for (int k = 0; k < NITER; ++k) {
            const int d = desc[k];
            if (d >= 0) {
                const int lo    = d & 0x3FFF;
                const int lrow  = (d >> 14) & 0x7F;
                const int lcol4 = (d >> 21) & 0x3F;
                const int gr = r0 - HALO_V + lrow;
                const int gc = c0 - HALO_H + lcol4 * 4;
                if (gr >= rlo && gr < rhi) {
                    const int upo = (lrow == 0     || gr == 0)     ? lo : lo - LDSW;
                    const int dno = (lrow == IH-1  || gr == RES-1) ? lo : lo + LDSW;
                    const float4 up  = *(const float4*)(&lds[upo]);
                    const float4 dn  = *(const float4*)(&lds[dno]);
                    const float4 lfq = *(const float4*)(&lds[lo - 4]);  // pad-safe
                    const float4 rtq = *(const float4*)(&lds[lo + 4]);  // pad-safe
                    const float lf = (gc == 0)         ? v[k].x : lfq.w;
                    const float rt = (gc + 3 == RES-1) ? v[k].w : rtq.x;
                    float4 nv;
                    {   const float m  = __uint_as_float(pk[k].x & 0x7fffffffu);
                        const float av = 0.25f*(up.x + dn.x + lf + v[k].y) + m;
                        nv.x = (pk[k].x >> 31) ? m : av; }
                    {   const float m  = __uint_as_float(pk[k].y & 0x7fffffffu);
                        const float av = 0.25f*(up.y + dn.y + v[k].x + v[k].z) + m;
                        nv.y = (pk[k].y >> 31) ? m : av; }
                    {   const float m  = __uint_as_float(pk[k].z & 0x7fffffffu);
                        const float av = 0.25f*(up.z + dn.z + v[k].y + v[k].w) + m;
                        nv.z = (pk[k].z >> 31) ? m : av; }
                    {   const float m  = __uint_as_float(pk[k].w & 0x7fffffffu);
                        const float av = 0.25f*(up.w + dn.w + v[k].z + rt) + m;
                        nv.w = (pk[k].w >> 31) ? m : av; }
                    if (gc + 0 >= clo && gc + 0 < chi) v[k].x = nv.x;
                    if (gc + 1 >= clo && gc + 1 < chi) v[k].y = nv.y;
                    if (gc + 2 >= clo && gc + 2 < chi) v[k].z = nv.z;
                    if (gc + 3 >= clo && gc + 3 < chi) v[k].w = nv.w;
                }
            }
        }
        if (s < T_STEPS) {
            __syncthreads();
#pragma unroll
            for (int k = 0; k < NITER; ++k)
                if (desc[k] >= 0) *(float4*)(&lds[desc[k] & 0x3FFF]) = v[k];
            __syncthreads();
        }
    }

    // ---- store output region ----
#pragma unroll
    for (int k = 0; k < NITER; ++k) {
        const int d = desc[k];
        if (d >= 0) {
            const int lrow  = (d >> 14) & 0x7F;
            const int lcol4 = (d >> 21) & 0x3F;
            if (lrow >= HALO_V && lrow < HALO_V + OH &&
                lcol4 >= HALO_H/4 && lcol4 < HALO_H/4 + OW/4) {
                const int gr = r0 - HALO_V + lrow;
                const int gc = c0 - HALO_H + lcol4 * 4;
                float4 o = v[k];
                if (FINAL) {
                    o.x = (pk[k].x >> 31) ? o.x : (o.x >= 1.0f ? 0.95f : o.x);
                    o.y = (pk[k].y >> 31) ? o.y : (o.y >= 1.0f ? 0.95f : o.y);
                    o.z = (pk[k].z >> 31) ? o.z : (o.z >= 1.0f ? 0.95f : o.z);
                    o.w = (pk[k].w >> 31) ? o.w : (o.w >= 1.0f ? 0.95f : o.w);
                }
                *(float4*)(Vout + (size_t)gr * RES + gc) = o;
            }
        }
    }
}

// ================= precompute: packed field + V0 =================
#define PB_OW 64
#define PB_OH 64
#define PB_HH 8
#define PB_HV 5
#define PB_IW (PB_OW + 2*PB_HH)   // 80
#define PB_IH (PB_OH + 2*PB_HV)   // 74
#define PB_NF4 (PB_IW/4)          // 20
#define PB_NSLOT (PB_NF4*PB_IH)   // 1480
#define PB_THR 256
#define PB_LDSW 84
#define PB_HLDSW 68

__global__ __launch_bounds__(PB_THR) void lap_precompute(
    const float* __restrict__ x, const float* __restrict__ bt,
    const float* __restrict__ bc, const float* __restrict__ C,
    float* __restrict__ V0, uint32_t* __restrict__ packed)
{
    __shared__ float ob[PB_IH * PB_LDSW];   // 24.9 KB
    __shared__ float hs[PB_IH * PB_HLDSW];  // 20.1 KB
    const int tid = threadIdx.x;
    const int r0 = blockIdx.y * PB_OH, c0 = blockIdx.x * PB_OW;

    // objects_bounds tile (zero outside image — conv 'SAME' zero-pads)
    for (int idx = tid; idx < PB_NSLOT; idx += PB_THR) {
        const int lrow = idx / PB_NF4;
        const int lcol4 = idx - lrow * PB_NF4;
        const int gr = r0 - PB_HV + lrow;
        const int gc = c0 - PB_HH + lcol4 * 4;
        float4 o = {0.f,0.f,0.f,0.f};
        if (gr >= 0 && gr < RES) {
            if (gc >= 0 && gc + 3 < RES) {
                const float4 b = *(const float4*)(bt + (size_t)gr*RES + gc);
                const float4 w = *(const float4*)(bc + (size_t)gr*RES + gc);
                o.x = (b.x == 1.f && w.x > 0.f) ? w.x : 0.f;
                o.y = (b.y == 1.f && w.y > 0.f) ? w.y : 0.f;
                o.z = (b.z == 1.f && w.z > 0.f) ? w.z : 0.f;
                o.w = (b.w == 1.f && w.w > 0.f) ? w.w : 0.f;
            } else {
#pragma unroll
                for (int e = 0; e < 4; ++e) {
                    const int cc = gc + e;
                    if (cc >= 0 && cc < RES) {
                        const float b = bt[(size_t)gr*RES + cc];
                        const float w = bc[(size_t)gr*RES + cc];
                        ((float*)&o)[e] = (b == 1.f && w > 0.f) ? w : 0.f;
                    }
                }
            }
        }
        *(float4*)(&ob[lrow*PB_LDSW + lcol4*4]) = o;
    }
    __syncthreads();

    // horizontal 11-sum: out col j uses ob cols [j+3, j+13]
    for (int idx = tid; idx < PB_IH * 16; idx += PB_THR) {
        const int lrow = idx >> 4;
        const int j4 = (idx & 15) << 2;
        const float* row = &ob[lrow * PB_LDSW];
        const float4 a0 = *(const float4*)(row + j4);
        const float4 a1 = *(const float4*)(row + j4 + 4);
        const float4 a2 = *(const float4*)(row + j4 + 8);
        const float4 a3 = *(const float4*)(row + j4 + 12);
        const float4 a4 = *(const float4*)(row + j4 + 16);
        const float common = a1.z + a1.w + a2.x + a2.y + a2.z + a2.w + a3.x + a3.y;
        float4 s;
        s.x = common + a0.w + a1.x + a1.y;
        s.y = common + a1.x + a1.y + a3.z;
        s.z = common + a1.y + a3.z + a3.w;
        s.w = common + a3.z + a3.w + a4.x;
        *(float4*)(&hs[lrow * PB_HLDSW + j4]) = s;
    }
    __syncthreads();

    // vertical 11-sum + pack + V0
    for (int idx = tid; idx < PB_OH * 16; idx += PB_THR) {
        const int i = idx >> 4;
        const int j4 = (idx & 15) << 2;
        float sx=0.f, sy=0.f, sz=0.f, sw=0.f;
#pragma unroll
        for (int d = 0; d < 11; ++d) {
            const float4 h = *(const float4*)(&hs[(i + d) * PB_HLDSW + j4]);
            sx += h.x; sy += h.y; sz += h.z; sw += h.w;
        }
        const int gr = r0 + i, gc = c0 + j4;
        const size_t g = (size_t)gr * RES + gc;
        const float4 xx  = *(const float4*)(x  + g);
        const float4 cc  = *(const float4*)(C  + g);
        const float4 btv = *(const float4*)(bt + g);
        const float4 bcv = *(const float4*)(bc + g);
        float4 v0; uint4 pko;
        const float es[4] = {sx, sy, sz, sw};
#pragma unroll
        for (int e = 0; e < 4; ++e) {
            const float cpos = fmaxf(((const float*)&cc)[e], 0.f);
            const bool interior = (((const float*)&btv)[e] == 0.0f);
            const float Cc = cpos + es[e] * (1.0f / 121.0f);
            const float bce = ((const float*)&bcv)[e];
            ((uint32_t*)&pko)[e] = interior ? __float_as_uint(Cc)
                                           : (__float_as_uint(bce) | 0x80000000u);
            ((float*)&v0)[e] = interior ? ((const float*)&xx)[e] : bce;
        }
        *(uint4*)(packed + g) = pko;
        *(float4*)(V0 + g) = v0;
    }
}

// ================= C_pos output =================
__global__ __launch_bounds__(256) void lap_cpos(
    const float* __restrict__ C, float* __restrict__ out2)
{
    const int idx = (blockIdx.x * 256 + threadIdx.x) * 4;
    const float4 c = *(const float4*)(C + idx);
    float4 o;
    o.x = fmaxf(c.x, 0.f); o.y = fmaxf(c.y, 0.f);
    o.z = fmaxf(c.z, 0.f); o.w = fmaxf(c.w, 0.f);
    *(float4*)(out2 + idx) = o;
}

extern "C" void kernel_launch(void* const* d_in, const int* in_sizes, int n_in,
                              void* d_out, int out_size, void* d_ws, size_t ws_size,
                              hipStream_t stream) {
    const float* x  = (const float*)d_in[0];
    const float* bt = (const float*)d_in[1];
    const float* bc = (const float*)d_in[2];
    const float* C  = (const float*)d_in[3];

    float*    out1   = (float*)d_out;                        // V ping / final out
    uint32_t* packed = (uint32_t*)((float*)d_out + N_CELLS); // packed field (until cpos)
    float*    vb     = (float*)d_ws;                         // V pong (64 MB)

    dim3 gP(RES / PB_OW, RES / PB_OH);
    lap_precompute<<<gP, PB_THR, 0, stream>>>(x, bt, bc, C, out1, packed);

    dim3 gF(RES / OW, RES / OH);   // 32 x 64
    lap_fused<0><<<gF, NTHR, 0, stream>>>(out1, packed, vb);
    lap_fused<0><<<gF, NTHR, 0, stream>>>(vb,   packed, out1);
    lap_fused<0><<<gF, NTHR, 0, stream>>>(out1, packed, vb);
    lap_fused<1><<<gF, NTHR, 0, stream>>>(vb,   packed, out1);

    lap_cpos<<<N_CELLS / 1024, 256, 0, stream>>>(C, (float*)d_out + N_CELLS);
}

// Round 7
// 614.554 us; speedup vs baseline: 2.8194x; 2.8194x over previous
//
#include <hip/hip_runtime.h>
#include <cstdint>

#define RES 4096
#define N_CELLS (RES*RES)

// ================= fused temporal-blocked Jacobi =================
// 4 launches x 5 steps. V ping-pongs between two LDS buffers (no persistent
// per-thread V registers -> no scratch). packed (Cc/bc, sign-bit flag) lives
// in 3 explicit uint4 registers per thread.
#define T_STEPS 5
#define OW 64
#define OH 64
#define HALO_V 5
#define HALO_H 8                 // >=T_STEPS; multiple of 4 for float4 alignment
#define IW (OW + 2*HALO_H)       // 80
#define IH (OH + 2*HALO_V)       // 74
#define NF4 (IW/4)               // 20
#define NSLOT (NF4*IH)           // 1480
#define NTHR 512
#define LDSW IW                  // 80 floats row stride
#define BUFSZ (IH*LDSW + 8)      // 5928 floats (+8 pad for lo±4 reads)
#define K2_LIM (NSLOT - 2*NTHR)  // 456: slot 2 active iff tid < 456

__device__ __forceinline__ void jstep(const float* __restrict__ src,
                                      float* __restrict__ dst,
                                      int lo, int gr, int gc, uint4 pk)
{
    const float4 ctr = *(const float4*)(src + lo);
    const int upo = (gr == 0)     ? lo : lo - LDSW;
    const int dno = (gr == RES-1) ? lo : lo + LDSW;
    const float4 up  = *(const float4*)(src + upo);
    const float4 dn  = *(const float4*)(src + dno);
    const float4 lfq = *(const float4*)(src + (lo - 4));   // pad-safe
    const float4 rtq = *(const float4*)(src + (lo + 4));   // pad-safe
    const float lf = (gc == 0)         ? ctr.x : lfq.w;
    const float rt = (gc + 3 == RES-1) ? ctr.w : rtq.x;
    float4 nv;
    {   const float m = __uint_as_float(pk.x & 0x7fffffffu);
        const float a = 0.25f*(up.x + dn.x + lf    + ctr.y) + m;
        nv.x = (pk.x >> 31) ? m : a; }
    {   const float m = __uint_as_float(pk.y & 0x7fffffffu);
        const float a = 0.25f*(up.y + dn.y + ctr.x + ctr.z) + m;
        nv.y = (pk.y >> 31) ? m : a; }
    {   const float m = __uint_as_float(pk.z & 0x7fffffffu);
        const float a = 0.25f*(up.z + dn.z + ctr.y + ctr.w) + m;
        nv.z = (pk.z >> 31) ? m : a; }
    {   const float m = __uint_as_float(pk.w & 0x7fffffffu);
        const float a = 0.25f*(up.w + dn.w + ctr.z + rt   ) + m;
        nv.w = (pk.w >> 31) ? m : a; }
    *(float4*)(dst + lo) = nv;
}

__device__ __forceinline__ void stage_slot(const float* __restrict__ Vin,
                                           const uint32_t* __restrict__ packed,
                                           float* __restrict__ bufA,
                                           int idx, int r0, int c0,
                                           int& lo, int& gr, int& gc, uint4& pk)
{
    const int lrow  = idx / NF4;            // const divisor -> mulhi
    const int lcol4 = idx - lrow * NF4;
    gr = r0 - HALO_V + lrow;
    gc = c0 - HALO_H + lcol4 * 4;
    lo = lrow * LDSW + lcol4 * 4;
    float4 vv; uint4 pp;
    const int rr = gr < 0 ? 0 : (gr > RES-1 ? RES-1 : gr);
    if (gc >= 0 && gc + 3 <= RES-1) {
        vv = *(const float4*)(Vin    + (size_t)rr * RES + gc);
        pp = *(const uint4*) (packed + (size_t)rr * RES + gc);
    } else {
#pragma unroll
        for (int e = 0; e < 4; ++e) {
            int cc = gc + e; cc = cc < 0 ? 0 : (cc > RES-1 ? RES-1 : cc);
            ((float*)&vv)[e]    = Vin   [(size_t)rr * RES + cc];
            ((uint32_t*)&pp)[e] = packed[(size_t)rr * RES + cc];
        }
    }
    *(float4*)(bufA + lo) = vv;
    pk = pp;
}

template<int FINAL>
__global__ __launch_bounds__(NTHR, 6) void lap_fused(
    const float* __restrict__ Vin, const uint32_t* __restrict__ packed,
    float* __restrict__ Vout)
{
    __shared__ float lds_raw[2 * BUFSZ];     // 47.4 KB
    float* bufA = lds_raw + 4;               // +4: pad for lo-4
    float* bufB = lds_raw + BUFSZ + 4;
    const int tid = threadIdx.x;
    const int r0 = blockIdx.y * OH;
    const int c0 = blockIdx.x * OW;

    // explicit per-slot scalars — NO arrays (round-5 lesson: arrays -> scratch)
    int lo0, gr0, gc0;  uint4 pk0;
    int lo1, gr1, gc1;  uint4 pk1;
    int lo2 = 0, gr2 = 0, gc2 = 0;  uint4 pk2 = {0u,0u,0u,0u};

    stage_slot(Vin, packed, bufA, tid,            r0, c0, lo0, gr0, gc0, pk0);
    stage_slot(Vin, packed, bufA, tid + NTHR,     r0, c0, lo1, gr1, gc1, pk1);
    if (tid < K2_LIM)
        stage_slot(Vin, packed, bufA, tid + 2*NTHR, r0, c0, lo2, gr2, gc2, pk2);
    __syncthreads();

    float* src = bufA;
    float* dst = bufB;
    for (int s = 1; s <= T_STEPS; ++s) {
        const int rlo = (r0 == 0)        ? 0   : (r0 - HALO_V + s);
        const int rhi = (r0 + OH == RES) ? RES : (r0 + OH + HALO_V - s);
        if (gr0 >= rlo && gr0 < rhi) jstep(src, dst, lo0, gr0, gc0, pk0);
        if (gr1 >= rlo && gr1 < rhi) jstep(src, dst, lo1, gr1, gc1, pk1);
        if (tid < K2_LIM && gr2 >= rlo && gr2 < rhi)
                                     jstep(src, dst, lo2, gr2, gc2, pk2);
        __syncthreads();
        float* t = src; src = dst; dst = t;
    }
    // final state is in `src` (last-written buffer)

#define STORE_SLOT(LO, GR, GC, PK, ACT)                                        \
    if ((ACT) && (GR) >= r0 && (GR) < r0 + OH && (GC) >= c0 && (GC) < c0 + OW) {\
        float4 o = *(const float4*)(src + (LO));                               \
        if (FINAL) {                                                           \
            o.x = ((PK).x >> 31) ? o.x : (o.x >= 1.0f ? 0.95f : o.x);          \
            o.y = ((PK).y >> 31) ? o.y : (o.y >= 1.0f ? 0.95f : o.y);          \
            o.z = ((PK).z >> 31) ? o.z : (o.z >= 1.0f ? 0.95f : o.z);          \
            o.w = ((PK).w >> 31) ? o.w : (o.w >= 1.0f ? 0.95f : o.w);          \
        }                                                                      \
        *(float4*)(Vout + (size_t)(GR) * RES + (GC)) = o;                      \
    }
    STORE_SLOT(lo0, gr0, gc0, pk0, true)
    STORE_SLOT(lo1, gr1, gc1, pk1, true)
    STORE_SLOT(lo2, gr2, gc2, pk2, tid < K2_LIM)
#undef STORE_SLOT
}

// ================= precompute: packed field + V0 =================
#define PB_OW 64
#define PB_OH 64
#define PB_HH 8
#define PB_HV 5
#define PB_IW (PB_OW + 2*PB_HH)   // 80
#define PB_IH (PB_OH + 2*PB_HV)   // 74
#define PB_NF4 (PB_IW/4)          // 20
#define PB_NSLOT (PB_NF4*PB_IH)   // 1480
#define PB_THR 256
#define PB_LDSW 84
#define PB_HLDSW 68

__global__ __launch_bounds__(PB_THR) void lap_precompute(
    const float* __restrict__ x, const float* __restrict__ bt,
    const float* __restrict__ bc, const float* __restrict__ C,
    float* __restrict__ V0, uint32_t* __restrict__ packed)
{
    __shared__ float ob[PB_IH * PB_LDSW];   // 24.9 KB
    __shared__ float hs[PB_IH * PB_HLDSW];  // 20.1 KB
    const int tid = threadIdx.x;
    const int r0 = blockIdx.y * PB_OH, c0 = blockIdx.x * PB_OW;

    // objects_bounds tile (zero outside image — conv 'SAME' zero-pads)
    for (int idx = tid; idx < PB_NSLOT; idx += PB_THR) {
        const int lrow = idx / PB_NF4;
        const int lcol4 = idx - lrow * PB_NF4;
        const int gr = r0 - PB_HV + lrow;
        const int gc = c0 - PB_HH + lcol4 * 4;
        float4 o = {0.f,0.f,0.f,0.f};
        if (gr >= 0 && gr < RES) {
            if (gc >= 0 && gc + 3 < RES) {
                const float4 b = *(const float4*)(bt + (size_t)gr*RES + gc);
                const float4 w = *(const float4*)(bc + (size_t)gr*RES + gc);
                o.x = (b.x == 1.f && w.x > 0.f) ? w.x : 0.f;
                o.y = (b.y == 1.f && w.y > 0.f) ? w.y : 0.f;
                o.z = (b.z == 1.f && w.z > 0.f) ? w.z : 0.f;
                o.w = (b.w == 1.f && w.w > 0.f) ? w.w : 0.f;
            } else {
#pragma unroll
                for (int e = 0; e < 4; ++e) {
                    const int cc = gc + e;
                    if (cc >= 0 && cc < RES) {
                        const float b = bt[(size_t)gr*RES + cc];
                        const float w = bc[(size_t)gr*RES + cc];
                        ((float*)&o)[e] = (b == 1.f && w > 0.f) ? w : 0.f;
                    }
                }
            }
        }
        *(float4*)(&ob[lrow*PB_LDSW + lcol4*4]) = o;
    }
    __syncthreads();

    // horizontal 11-sum: out col j uses ob cols [j+3, j+13]
    for (int idx = tid; idx < PB_IH * 16; idx += PB_THR) {
        const int lrow = idx >> 4;
        const int j4 = (idx & 15) << 2;
        const float* row = &ob[lrow * PB_LDSW];
        const float4 a0 = *(const float4*)(row + j4);
        const float4 a1 = *(const float4*)(row + j4 + 4);
        const float4 a2 = *(const float4*)(row + j4 + 8);
        const float4 a3 = *(const float4*)(row + j4 + 12);
        const float4 a4 = *(const float4*)(row + j4 + 16);
        const float common = a1.z + a1.w + a2.x + a2.y + a2.z + a2.w + a3.x + a3.y;
        float4 s;
        s.x = common + a0.w + a1.x + a1.y;
        s.y = common + a1.x + a1.y + a3.z;
        s.z = common + a1.y + a3.z + a3.w;
        s.w = common + a3.z + a3.w + a4.x;
        *(float4*)(&hs[lrow * PB_HLDSW + j4]) = s;
    }
    __syncthreads();

    // vertical 11-sum + pack + V0
    for (int idx = tid; idx < PB_OH * 16; idx += PB_THR) {
        const int i = idx >> 4;
        const int j4 = (idx & 15) << 2;
        float sx=0.f, sy=0.f, sz=0.f, sw=0.f;
#pragma unroll
        for (int d = 0; d < 11; ++d) {
            const float4 h = *(const float4*)(&hs[(i + d) * PB_HLDSW + j4]);
            sx += h.x; sy += h.y; sz += h.z; sw += h.w;
        }
        const int gr = r0 + i, gc = c0 + j4;
        const size_t g = (size_t)gr * RES + gc;
        const float4 xx  = *(const float4*)(x  + g);
        const float4 cc  = *(const float4*)(C  + g);
        const float4 btv = *(const float4*)(bt + g);
        const float4 bcv = *(const float4*)(bc + g);
        float4 v0; uint4 pko;
        const float es[4] = {sx, sy, sz, sw};
#pragma unroll
        for (int e = 0; e < 4; ++e) {
            const float cpos = fmaxf(((const float*)&cc)[e], 0.f);
            const bool interior = (((const float*)&btv)[e] == 0.0f);
            const float Cc = cpos + es[e] * (1.0f / 121.0f);
            const float bce = ((const float*)&bcv)[e];
            ((uint32_t*)&pko)[e] = interior ? __float_as_uint(Cc)
                                           : (__float_as_uint(bce) | 0x80000000u);
            ((float*)&v0)[e] = interior ? ((const float*)&xx)[e] : bce;
        }
        *(uint4*)(packed + g) = pko;
        *(float4*)(V0 + g) = v0;
    }
}

// ================= C_pos output =================
__global__ __launch_bounds__(256) void lap_cpos(
    const float* __restrict__ C, float* __restrict__ out2)
{
    const int idx = (blockIdx.x * 256 + threadIdx.x) * 4;
    const float4 c = *(const float4*)(C + idx);
    float4 o;
    o.x = fmaxf(c.x, 0.f); o.y = fmaxf(c.y, 0.f);
    o.z = fmaxf(c.z, 0.f); o.w = fmaxf(c.w, 0.f);
    *(float4*)(out2 + idx) = o;
}

extern "C" void kernel_launch(void* const* d_in, const int* in_sizes, int n_in,
                              void* d_out, int out_size, void* d_ws, size_t ws_size,
                              hipStream_t stream) {
    const float* x  = (const float*)d_in[0];
    const float* bt = (const float*)d_in[1];
    const float* bc = (const float*)d_in[2];
    const float* C  = (const float*)d_in[3];

    float*    out1   = (float*)d_out;                        // V ping / final out
    uint32_t* packed = (uint32_t*)((float*)d_out + N_CELLS); // packed field (until cpos)
    float*    vb     = (float*)d_ws;                         // V pong (64 MB)

    dim3 gP(RES / PB_OW, RES / PB_OH);
    lap_precompute<<<gP, PB_THR, 0, stream>>>(x, bt, bc, C, out1, packed);

    dim3 gF(RES / OW, RES / OH);   // 64 x 64
    lap_fused<0><<<gF, NTHR, 0, stream>>>(out1, packed, vb);
    lap_fused<0><<<gF, NTHR, 0, stream>>>(vb,   packed, out1);
    lap_fused<0><<<gF, NTHR, 0, stream>>>(out1, packed, vb);
    lap_fused<1><<<gF, NTHR, 0, stream>>>(vb,   packed, out1);

    lap_cpos<<<N_CELLS / 1024, 256, 0, stream>>>(C, (float*)d_out + N_CELLS);
}

// Round 8
// 594.863 us; speedup vs baseline: 2.9127x; 1.0331x over previous
//
#include <hip/hip_runtime.h>
#include <cstdint>

#define RES 4096
#define N_CELLS (RES*RES)

// ================= fused temporal-blocked Jacobi =================
// 4 launches x 5 steps. SINGLE LDS V buffer; per-step update carried in
// registers across a barrier (read-phase / write-phase). packed (Cc/bc,
// sign-bit flag) in 3 explicit uint4 registers. No arrays -> no scratch.
#define T_STEPS 5
#define OW 64
#define OH 64
#define HALO_V 5
#define HALO_H 8                 // >=T_STEPS; multiple of 4 for float4 alignment
#define IW (OW + 2*HALO_H)       // 80
#define IH (OH + 2*HALO_V)       // 74
#define NF4 (IW/4)               // 20
#define NSLOT (NF4*IH)           // 1480
#define NTHR 512
#define LDSW IW                  // 80 floats row stride
#define BUFSZ (IH*LDSW + 8)      // 5928 floats (+8 pad for lo±4 reads)
#define K2_LIM (NSLOT - 2*NTHR)  // 456: slot 2 active iff tid < 456

__device__ __forceinline__ float4 jcalc(const float* buf,
                                        int lo, int gr, int gc, uint4 pk)
{
    const float4 ctr = *(const float4*)(buf + lo);
    const int upo = (gr == 0)     ? lo : lo - LDSW;
    const int dno = (gr == RES-1) ? lo : lo + LDSW;
    const float4 up  = *(const float4*)(buf + upo);
    const float4 dn  = *(const float4*)(buf + dno);
    const float4 lfq = *(const float4*)(buf + (lo - 4));   // pad-safe
    const float4 rtq = *(const float4*)(buf + (lo + 4));   // pad-safe
    const float lf = (gc == 0)         ? ctr.x : lfq.w;
    const float rt = (gc + 3 == RES-1) ? ctr.w : rtq.x;
    float4 nv;
    {   const float m = __uint_as_float(pk.x & 0x7fffffffu);
        const float a = 0.25f*(up.x + dn.x + lf    + ctr.y) + m;
        nv.x = (pk.x >> 31) ? m : a; }
    {   const float m = __uint_as_float(pk.y & 0x7fffffffu);
        const float a = 0.25f*(up.y + dn.y + ctr.x + ctr.z) + m;
        nv.y = (pk.y >> 31) ? m : a; }
    {   const float m = __uint_as_float(pk.z & 0x7fffffffu);
        const float a = 0.25f*(up.z + dn.z + ctr.y + ctr.w) + m;
        nv.z = (pk.z >> 31) ? m : a; }
    {   const float m = __uint_as_float(pk.w & 0x7fffffffu);
        const float a = 0.25f*(up.w + dn.w + ctr.z + rt   ) + m;
        nv.w = (pk.w >> 31) ? m : a; }
    return nv;
}

__device__ __forceinline__ void stage_slot(const float* __restrict__ Vin,
                                           const uint32_t* __restrict__ packed,
                                           float* buf,
                                           int idx, int r0, int c0,
                                           int& lo, int& gr, int& gc, uint4& pk)
{
    const int lrow  = idx / NF4;            // const divisor -> mulhi
    const int lcol4 = idx - lrow * NF4;
    gr = r0 - HALO_V + lrow;
    gc = c0 - HALO_H + lcol4 * 4;
    lo = lrow * LDSW + lcol4 * 4;
    float4 vv; uint4 pp;
    const int rr = gr < 0 ? 0 : (gr > RES-1 ? RES-1 : gr);
    if (gc >= 0 && gc + 3 <= RES-1) {
        vv = *(const float4*)(Vin    + (size_t)rr * RES + gc);
        pp = *(const uint4*) (packed + (size_t)rr * RES + gc);
    } else {
#pragma unroll
        for (int e = 0; e < 4; ++e) {
            int cc = gc + e; cc = cc < 0 ? 0 : (cc > RES-1 ? RES-1 : cc);
            ((float*)&vv)[e]    = Vin   [(size_t)rr * RES + cc];
            ((uint32_t*)&pp)[e] = packed[(size_t)rr * RES + cc];
        }
    }
    *(float4*)(buf + lo) = vv;
    pk = pp;
}

template<int FINAL>
__global__ __launch_bounds__(NTHR, 8) void lap_fused(
    const float* __restrict__ Vin, const uint32_t* __restrict__ packed,
    float* __restrict__ Vout)
{
    __shared__ float lds_raw[BUFSZ];         // 23.7 KB -> 4 blocks/CU (wave-capped)
    float* buf = lds_raw + 4;                // +4: pad for lo-4
    const int tid = threadIdx.x;
    const int r0 = blockIdx.y * OH;
    const int c0 = blockIdx.x * OW;

    // explicit per-slot scalars — NO arrays (round-5 lesson: arrays -> scratch)
    int lo0, gr0, gc0;  uint4 pk0;
    int lo1, gr1, gc1;  uint4 pk1;
    int lo2 = 0, gr2 = 0, gc2 = 0;  uint4 pk2 = {0u,0u,0u,0u};

    stage_slot(Vin, packed, buf, tid,            r0, c0, lo0, gr0, gc0, pk0);
    stage_slot(Vin, packed, buf, tid + NTHR,     r0, c0, lo1, gr1, gc1, pk1);
    if (tid < K2_LIM)
        stage_slot(Vin, packed, buf, tid + 2*NTHR, r0, c0, lo2, gr2, gc2, pk2);
    __syncthreads();

    // steps 1..T-1: read-phase -> barrier -> write-phase -> barrier
    for (int s = 1; s < T_STEPS; ++s) {
        const int rlo = (r0 == 0)        ? 0   : (r0 - HALO_V + s);
        const int rhi = (r0 + OH == RES) ? RES : (r0 + OH + HALO_V - s);
        const bool a0 = (gr0 >= rlo) && (gr0 < rhi);
        const bool a1 = (gr1 >= rlo) && (gr1 < rhi);
        const bool a2 = (tid < K2_LIM) && (gr2 >= rlo) && (gr2 < rhi);
        float4 nv0, nv1, nv2;
        if (a0) nv0 = jcalc(buf, lo0, gr0, gc0, pk0);
        if (a1) nv1 = jcalc(buf, lo1, gr1, gc1, pk1);
        if (a2) nv2 = jcalc(buf, lo2, gr2, gc2, pk2);
        __syncthreads();
        if (a0) *(float4*)(buf + lo0) = nv0;
        if (a1) *(float4*)(buf + lo1) = nv1;
        if (a2) *(float4*)(buf + lo2) = nv2;
        __syncthreads();
    }

    // final step: compute output cells only, store straight from registers
#define FINAL_SLOT(LO, GR, GC, PK, ACT)                                        \
    if ((ACT) && (GR) >= r0 && (GR) < r0 + OH && (GC) >= c0 && (GC) < c0 + OW) {\
        float4 o = jcalc(buf, (LO), (GR), (GC), (PK));                         \
        if (FINAL) {                                                           \
            o.x = ((PK).x >> 31) ? o.x : (o.x >= 1.0f ? 0.95f : o.x);          \
            o.y = ((PK).y >> 31) ? o.y : (o.y >= 1.0f ? 0.95f : o.y);          \
            o.z = ((PK).z >> 31) ? o.z : (o.z >= 1.0f ? 0.95f : o.z);          \
            o.w = ((PK).w >> 31) ? o.w : (o.w >= 1.0f ? 0.95f : o.w);          \
        }                                                                      \
        *(float4*)(Vout + (size_t)(GR) * RES + (GC)) = o;                      \
    }
    FINAL_SLOT(lo0, gr0, gc0, pk0, true)
    FINAL_SLOT(lo1, gr1, gc1, pk1, true)
    FINAL_SLOT(lo2, gr2, gc2, pk2, tid < K2_LIM)
#undef FINAL_SLOT
}

// ================= precompute: packed field + V0 =================
#define PB_OW 64
#define PB_OH 64
#define PB_HH 8
#define PB_HV 5
#define PB_IW (PB_OW + 2*PB_HH)   // 80
#define PB_IH (PB_OH + 2*PB_HV)   // 74
#define PB_NF4 (PB_IW/4)          // 20
#define PB_NSLOT (PB_NF4*PB_IH)   // 1480
#define PB_THR 512
#define PB_LDSW 84
#define PB_HLDSW 68

__global__ __launch_bounds__(PB_THR, 6) void lap_precompute(
    const float* __restrict__ x, const float* __restrict__ bt,
    const float* __restrict__ bc, const float* __restrict__ C,
    float* __restrict__ V0, uint32_t* __restrict__ packed)
{
    __shared__ float ob[PB_IH * PB_LDSW];   // 24.9 KB
    __shared__ float hs[PB_IH * PB_HLDSW];  // 20.1 KB
    const int tid = threadIdx.x;
    const int r0 = blockIdx.y * PB_OH, c0 = blockIdx.x * PB_OW;

    // objects_bounds tile (zero outside image — conv 'SAME' zero-pads)
    for (int idx = tid; idx < PB_NSLOT; idx += PB_THR) {
        const int lrow = idx / PB_NF4;
        const int lcol4 = idx - lrow * PB_NF4;
        const int gr = r0 - PB_HV + lrow;
        const int gc = c0 - PB_HH + lcol4 * 4;
        float4 o = {0.f,0.f,0.f,0.f};
        if (gr >= 0 && gr < RES) {
            if (gc >= 0 && gc + 3 < RES) {
                const float4 b = *(const float4*)(bt + (size_t)gr*RES + gc);
                const float4 w = *(const float4*)(bc + (size_t)gr*RES + gc);
                o.x = (b.x == 1.f && w.x > 0.f) ? w.x : 0.f;
                o.y = (b.y == 1.f && w.y > 0.f) ? w.y : 0.f;
                o.z = (b.z == 1.f && w.z > 0.f) ? w.z : 0.f;
                o.w = (b.w == 1.f && w.w > 0.f) ? w.w : 0.f;
            } else {
#pragma unroll
                for (int e = 0; e < 4; ++e) {
                    const int cc = gc + e;
                    if (cc >= 0 && cc < RES) {
                        const float b = bt[(size_t)gr*RES + cc];
                        const float w = bc[(size_t)gr*RES + cc];
                        ((float*)&o)[e] = (b == 1.f && w > 0.f) ? w : 0.f;
                    }
                }
            }
        }
        *(float4*)(&ob[lrow*PB_LDSW + lcol4*4]) = o;
    }
    __syncthreads();

    // horizontal 11-sum: out col j uses ob cols [j+3, j+13]
    for (int idx = tid; idx < PB_IH * 16; idx += PB_THR) {
        const int lrow = idx >> 4;
        const int j4 = (idx & 15) << 2;
        const float* row = &ob[lrow * PB_LDSW];
        const float4 a0 = *(const float4*)(row + j4);
        const float4 a1 = *(const float4*)(row + j4 + 4);
        const float4 a2 = *(const float4*)(row + j4 + 8);
        const float4 a3 = *(const float4*)(row + j4 + 12);
        const float4 a4 = *(const float4*)(row + j4 + 16);
        const float common = a1.z + a1.w + a2.x + a2.y + a2.z + a2.w + a3.x + a3.y;
        float4 s;
        s.x = common + a0.w + a1.x + a1.y;
        s.y = common + a1.x + a1.y + a3.z;
        s.z = common + a1.y + a3.z + a3.w;
        s.w = common + a3.z + a3.w + a4.x;
        *(float4*)(&hs[lrow * PB_HLDSW + j4]) = s;
    }
    __syncthreads();

    // vertical 11-sum + pack + V0
    for (int idx = tid; idx < PB_OH * 16; idx += PB_THR) {
        const int i = idx >> 4;
        const int j4 = (idx & 15) << 2;
        float sx=0.f, sy=0.f, sz=0.f, sw=0.f;
#pragma unroll
        for (int d = 0; d < 11; ++d) {
            const float4 h = *(const float4*)(&hs[(i + d) * PB_HLDSW + j4]);
            sx += h.x; sy += h.y; sz += h.z; sw += h.w;
        }
        const int gr = r0 + i, gc = c0 + j4;
        const size_t g = (size_t)gr * RES + gc;
        const float4 xx  = *(const float4*)(x  + g);
        const float4 cc  = *(const float4*)(C  + g);
        const float4 btv = *(const float4*)(bt + g);
        const float4 bcv = *(const float4*)(bc + g);
        float4 v0; uint4 pko;
        const float es[4] = {sx, sy, sz, sw};
#pragma unroll
        for (int e = 0; e < 4; ++e) {
            const float cpos = fmaxf(((const float*)&cc)[e], 0.f);
            const bool interior = (((const float*)&btv)[e] == 0.0f);
            const float Cc = cpos + es[e] * (1.0f / 121.0f);
            const float bce = ((const float*)&bcv)[e];
            ((uint32_t*)&pko)[e] = interior ? __float_as_uint(Cc)
                                           : (__float_as_uint(bce) | 0x80000000u);
            ((float*)&v0)[e] = interior ? ((const float*)&xx)[e] : bce;
        }
        *(uint4*)(packed + g) = pko;
        *(float4*)(V0 + g) = v0;
    }
}

// ================= C_pos output =================
__global__ __launch_bounds__(256) void lap_cpos(
    const float* __restrict__ C, float* __restrict__ out2)
{
    const int idx = (blockIdx.x * 256 + threadIdx.x) * 4;
    const float4 c = *(const float4*)(C + idx);
    float4 o;
    o.x = fmaxf(c.x, 0.f); o.y = fmaxf(c.y, 0.f);
    o.z = fmaxf(c.z, 0.f); o.w = fmaxf(c.w, 0.f);
    *(float4*)(out2 + idx) = o;
}

extern "C" void kernel_launch(void* const* d_in, const int* in_sizes, int n_in,
                              void* d_out, int out_size, void* d_ws, size_t ws_size,
                              hipStream_t stream) {
    const float* x  = (const float*)d_in[0];
    const float* bt = (const float*)d_in[1];
    const float* bc = (const float*)d_in[2];
    const float* C  = (const float*)d_in[3];

    float*    out1   = (float*)d_out;                        // V ping / final out
    uint32_t* packed = (uint32_t*)((float*)d_out + N_CELLS); // packed field (until cpos)
    float*    vb     = (float*)d_ws;                         // V pong (64 MB)

    dim3 gP(RES / PB_OW, RES / PB_OH);
    lap_precompute<<<gP, PB_THR, 0, stream>>>(x, bt, bc, C, out1, packed);

    dim3 gF(RES / OW, RES / OH);   // 64 x 64
    lap_fused<0><<<gF, NTHR, 0, stream>>>(out1, packed, vb);
    lap_fused<0><<<gF, NTHR, 0, stream>>>(vb,   packed, out1);
    lap_fused<0><<<gF, NTHR, 0, stream>>>(out1, packed, vb);
    lap_fused<1><<<gF, NTHR, 0, stream>>>(vb,   packed, out1);

    lap_cpos<<<N_CELLS / 1024, 256, 0, stream>>>(C, (float*)d_out + N_CELLS);
}

// Round 9
// 548.845 us; speedup vs baseline: 3.1569x; 1.0838x over previous
//
#include <hip/hip_runtime.h>
#include <cstdint>

#define RES 4096
#define N_CELLS (RES*RES)

// ============== register-marching temporal-blocked Jacobi ==============
// 2 launches x T=10 steps. Each thread owns a 4-row x 1-float4-col strip in
// REGISTERS. up/dn in-register; lf/rt via shfl (adjacent lane = adjacent col);
// only strip-boundary rows cross LDS (parity dbuf, 1 barrier/step).
// Tile: 104x104 output, halo 12 -> loaded 128x128. 1024 thr = 32 cols x 32 strips.
#define MT_OW 104
#define MT_OH 104
#define MT_HH 12
#define MT_HV 12
#define MT_IW 128                 // floats = 32 float4 cols (half-wave = full row)
#define MT_IH 128                 // 32 strips x 4 rows
#define MT_GRID 40                // ceil(4096/104); edge tiles masked

__device__ __forceinline__ float4 jrow(float4 up, float4 dn, const float4 cur,
                                       const uint4 pk, const int gr, const int gc)
{
    float lf = __shfl_up(cur.w, 1);     // adjacent-lane column exchange
    float rt = __shfl_down(cur.x, 1);
    lf = (gc == 0)         ? cur.x : lf;   // image-left replicate (bypasses shfl)
    rt = (gc + 3 == RES-1) ? cur.w : rt;   // image-right replicate
    if (gr <= 0)       up = cur;           // gr==0 replicate; gr<0 garbage rows
    if (gr >= RES - 1) dn = cur;           // gr==RES-1 replicate; OOB rows garbage
    float4 nv;
    {   const float m = __uint_as_float(pk.x & 0x7fffffffu);
        nv.x = (pk.x >> 31) ? m : 0.25f*(up.x + dn.x + lf    + cur.y) + m; }
    {   const float m = __uint_as_float(pk.y & 0x7fffffffu);
        nv.y = (pk.y >> 31) ? m : 0.25f*(up.y + dn.y + cur.x + cur.z) + m; }
    {   const float m = __uint_as_float(pk.z & 0x7fffffffu);
        nv.z = (pk.z >> 31) ? m : 0.25f*(up.z + dn.z + cur.y + cur.w) + m; }
    {   const float m = __uint_as_float(pk.w & 0x7fffffffu);
        nv.w = (pk.w >> 31) ? m : 0.25f*(up.w + dn.w + cur.z + rt   ) + m; }
    return nv;
}

template<int T, int FINAL>
__global__ __launch_bounds__(1024, 8) void lap_march(
    const float* __restrict__ Vin, const uint32_t* __restrict__ packed,
    float* __restrict__ Vout)
{
    __shared__ float4 bnd[2][32][2][32];   // parity x strip x {top,bot} x col = 64 KB
    const int tid   = threadIdx.x;
    const int c     = tid & 31;            // float4-column
    const int strip = tid >> 5;            // 4-row strip
    const int o0 = blockIdx.x * MT_OW;
    const int r0 = blockIdx.y * MT_OH;
    const int gc  = o0 - MT_HH + 4*c;      // this thread's column (4 floats)
    const int grb = r0 - MT_HV + 4*strip;  // row of j=0

    // ---- stage: global -> registers (clamped) ----
    float4 v0, v1, v2, v3;  uint4 p0, p1, p2, p3;
    {
        auto loadrow = [&](int gr, float4& vv, uint4& pp) {
            const int rr = gr < 0 ? 0 : (gr > RES-1 ? RES-1 : gr);
            const size_t base = (size_t)rr * RES;
            if ((unsigned)gc < (unsigned)RES) {        // aligned: gc in [0,4092]
                vv = *(const float4*)(Vin + base + gc);
                pp = *(const uint4*)(packed + base + gc);
            } else {
#pragma unroll
                for (int e = 0; e < 4; ++e) {
                    int cc = gc + e; cc = cc < 0 ? 0 : (cc > RES-1 ? RES-1 : cc);
                    ((float*)&vv)[e]    = Vin   [base + cc];
                    ((uint32_t*)&pp)[e] = packed[base + cc];
                }
            }
        };
        loadrow(grb + 0, v0, p0);
        loadrow(grb + 1, v1, p1);
        loadrow(grb + 2, v2, p2);
        loadrow(grb + 3, v3, p3);
    }

    // ---- T steps, 1 barrier each (parity-dbuf boundary exchange) ----
    for (int s = 1; s <= T; ++s) {
        const int par = s & 1;
        bnd[par][strip][0][c] = v0;        // my strip's top row (old values)
        bnd[par][strip][1][c] = v3;        // my strip's bottom row
        __syncthreads();
        const int sa = strip > 0  ? strip - 1 : 0;    // clamped: edge = garbage-tolerant
        const int sb = strip < 31 ? strip + 1 : 31;
        const float4 above = bnd[par][sa][1][c];
        const float4 below = bnd[par][sb][0][c];
        const float4 t0 = v0, t1 = v1, t2 = v2;       // old values for row j+1's up
        v0 = jrow(above, v1,    v0, p0, grb + 0, gc);
        v1 = jrow(t0,    v2,    v1, p1, grb + 1, gc);
        v2 = jrow(t1,    v3,    v2, p2, grb + 2, gc);
        v3 = jrow(t2,    below, v3, p3, grb + 3, gc);
    }

    // ---- store output region (cols c in [3,29) = [o0, o0+104)) ----
    if (c >= 3 && c < 29 && gc < RES) {
#define STORE_ROW(J, VV, PP)                                                   \
        {   const int gr = grb + (J);                                          \
            if (gr >= r0 && gr < r0 + MT_OH && gr < RES) {                     \
                float4 o = VV;                                                 \
                if (FINAL) {                                                   \
                    o.x = ((PP).x >> 31) ? o.x : (o.x >= 1.0f ? 0.95f : o.x);  \
                    o.y = ((PP).y >> 31) ? o.y : (o.y >= 1.0f ? 0.95f : o.y);  \
                    o.z = ((PP).z >> 31) ? o.z : (o.z >= 1.0f ? 0.95f : o.z);  \
                    o.w = ((PP).w >> 31) ? o.w : (o.w >= 1.0f ? 0.95f : o.w);  \
                }                                                              \
                *(float4*)(Vout + (size_t)gr * RES + gc) = o;                  \
            }                                                                  \
        }
        STORE_ROW(0, v0, p0)
        STORE_ROW(1, v1, p1)
        STORE_ROW(2, v2, p2)
        STORE_ROW(3, v3, p3)
#undef STORE_ROW
    }
}

// ================= precompute: packed field + V0 (unchanged) =================
#define PB_OW 64
#define PB_OH 64
#define PB_HH 8
#define PB_HV 5
#define PB_IW (PB_OW + 2*PB_HH)   // 80
#define PB_IH (PB_OH + 2*PB_HV)   // 74
#define PB_NF4 (PB_IW/4)          // 20
#define PB_NSLOT (PB_NF4*PB_IH)   // 1480
#define PB_THR 512
#define PB_LDSW 84
#define PB_HLDSW 68

__global__ __launch_bounds__(PB_THR, 6) void lap_precompute(
    const float* __restrict__ x, const float* __restrict__ bt,
    const float* __restrict__ bc, const float* __restrict__ C,
    float* __restrict__ V0, uint32_t* __restrict__ packed)
{
    __shared__ float ob[PB_IH * PB_LDSW];   // 24.9 KB
    __shared__ float hs[PB_IH * PB_HLDSW];  // 20.1 KB
    const int tid = threadIdx.x;
    const int r0 = blockIdx.y * PB_OH, c0 = blockIdx.x * PB_OW;

    for (int idx = tid; idx < PB_NSLOT; idx += PB_THR) {
        const int lrow = idx / PB_NF4;
        const int lcol4 = idx - lrow * PB_NF4;
        const int gr = r0 - PB_HV + lrow;
        const int gc = c0 - PB_HH + lcol4 * 4;
        float4 o = {0.f,0.f,0.f,0.f};
        if (gr >= 0 && gr < RES) {
            if (gc >= 0 && gc + 3 < RES) {
                const float4 b = *(const float4*)(bt + (size_t)gr*RES + gc);
                const float4 w = *(const float4*)(bc + (size_t)gr*RES + gc);
                o.x = (b.x == 1.f && w.x > 0.f) ? w.x : 0.f;
                o.y = (b.y == 1.f && w.y > 0.f) ? w.y : 0.f;
                o.z = (b.z == 1.f && w.z > 0.f) ? w.z : 0.f;
                o.w = (b.w == 1.f && w.w > 0.f) ? w.w : 0.f;
            } else {
#pragma unroll
                for (int e = 0; e < 4; ++e) {
                    const int cc = gc + e;
                    if (cc >= 0 && cc < RES) {
                        const float b = bt[(size_t)gr*RES + cc];
                        const float w = bc[(size_t)gr*RES + cc];
                        ((float*)&o)[e] = (b == 1.f && w > 0.f) ? w : 0.f;
                    }
                }
            }
        }
        *(float4*)(&ob[lrow*PB_LDSW + lcol4*4]) = o;
    }
    __syncthreads();

    for (int idx = tid; idx < PB_IH * 16; idx += PB_THR) {
        const int lrow = idx >> 4;
        const int j4 = (idx & 15) << 2;
        const float* row = &ob[lrow * PB_LDSW];
        const float4 a0 = *(const float4*)(row + j4);
        const float4 a1 = *(const float4*)(row + j4 + 4);
        const float4 a2 = *(const float4*)(row + j4 + 8);
        const float4 a3 = *(const float4*)(row + j4 + 12);
        const float4 a4 = *(const float4*)(row + j4 + 16);
        const float common = a1.z + a1.w + a2.x + a2.y + a2.z + a2.w + a3.x + a3.y;
        float4 s;
        s.x = common + a0.w + a1.x + a1.y;
        s.y = common + a1.x + a1.y + a3.z;
        s.z = common + a1.y + a3.z + a3.w;
        s.w = common + a3.z + a3.w + a4.x;
        *(float4*)(&hs[lrow * PB_HLDSW + j4]) = s;
    }
    __syncthreads();

    for (int idx = tid; idx < PB_OH * 16; idx += PB_THR) {
        const int i = idx >> 4;
        const int j4 = (idx & 15) << 2;
        float sx=0.f, sy=0.f, sz=0.f, sw=0.f;
#pragma unroll
        for (int d = 0; d < 11; ++d) {
            const float4 h = *(const float4*)(&hs[(i + d) * PB_HLDSW + j4]);
            sx += h.x; sy += h.y; sz += h.z; sw += h.w;
        }
        const int gr = r0 + i, gc = c0 + j4;
        const size_t g = (size_t)gr * RES + gc;
        const float4 xx  = *(const float4*)(x  + g);
        const float4 cc  = *(const float4*)(C  + g);
        const float4 btv = *(const float4*)(bt + g);
        const float4 bcv = *(const float4*)(bc + g);
        float4 v0; uint4 pko;
        const float es[4] = {sx, sy, sz, sw};
#pragma unroll
        for (int e = 0; e < 4; ++e) {
            const float cpos = fmaxf(((const float*)&cc)[e], 0.f);
            const bool interior = (((const float*)&btv)[e] == 0.0f);
            const float Cc = cpos + es[e] * (1.0f / 121.0f);
            const float bce = ((const float*)&bcv)[e];
            ((uint32_t*)&pko)[e] = interior ? __float_as_uint(Cc)
                                           : (__float_as_uint(bce) | 0x80000000u);
            ((float*)&v0)[e] = interior ? ((const float*)&xx)[e] : bce;
        }
        *(uint4*)(packed + g) = pko;
        *(float4*)(V0 + g) = v0;
    }
}

// ================= C_pos output =================
__global__ __launch_bounds__(256) void lap_cpos(
    const float* __restrict__ C, float* __restrict__ out2)
{
    const int idx = (blockIdx.x * 256 + threadIdx.x) * 4;
    const float4 c = *(const float4*)(C + idx);
    float4 o;
    o.x = fmaxf(c.x, 0.f); o.y = fmaxf(c.y, 0.f);
    o.z = fmaxf(c.z, 0.f); o.w = fmaxf(c.w, 0.f);
    *(float4*)(out2 + idx) = o;
}

extern "C" void kernel_launch(void* const* d_in, const int* in_sizes, int n_in,
                              void* d_out, int out_size, void* d_ws, size_t ws_size,
                              hipStream_t stream) {
    const float* x  = (const float*)d_in[0];
    const float* bt = (const float*)d_in[1];
    const float* bc = (const float*)d_in[2];
    const float* C  = (const float*)d_in[3];

    float*    out1   = (float*)d_out;                        // V ping / final out
    uint32_t* packed = (uint32_t*)((float*)d_out + N_CELLS); // packed field (until cpos)
    float*    vb     = (float*)d_ws;                         // V pong (64 MB)

    dim3 gP(RES / PB_OW, RES / PB_OH);
    lap_precompute<<<gP, PB_THR, 0, stream>>>(x, bt, bc, C, out1, packed);

    dim3 gM(MT_GRID, MT_GRID);   // 40 x 40, partial edge tiles masked
    lap_march<10, 0><<<gM, 1024, 0, stream>>>(out1, packed, vb);
    lap_march<10, 1><<<gM, 1024, 0, stream>>>(vb, packed, out1);

    lap_cpos<<<N_CELLS / 1024, 256, 0, stream>>>(C, (float*)d_out + N_CELLS);
}